// Round 1
// baseline (4479.473 us; speedup 1.0000x reference)
//
#include <hip/hip_runtime.h>
#include <cstdint>
#include <cstddef>

#define NNODES 100000
#define NEDGES 1600000
#define IN_DIM 256
#define HID 128
#define HEADS 8
#define DH 16
#define NCLS 64
#define SLOPE 0.2f

// ---------------- fp32 tiled GEMM: C[M,NC] = A[M,K] @ B[K,NC] ----------------
// BM=64, BN=64, BK=32, 256 threads, 4x4 microtile. K, NC multiples of 32/64.
#define BM 64
#define BN 64
#define BK 32

__global__ __launch_bounds__(256) void sgemm_kernel(const float* __restrict__ A,
                                                    const float* __restrict__ B,
                                                    float* __restrict__ C,
                                                    int M, int K, int NC) {
    __shared__ float As[BK][BM];       // transposed: As[k][row]
    __shared__ float Bs[BK][BN + 4];   // padded
    const int brow = blockIdx.x * BM;
    const int bcol = blockIdx.y * BN;
    const int tid = threadIdx.x;
    const int tx = tid & 15;
    const int ty = tid >> 4;
    float acc[4][4] = {};

    for (int k0 = 0; k0 < K; k0 += BK) {
#pragma unroll
        for (int i = 0; i < 2; ++i) {
            int idx = tid + i * 256;            // 0..511 -> 512 float4 of A tile
            int r   = idx >> 3;                 // 64 rows, 8 float4 per row
            int kc  = (idx & 7) << 2;
            float4 v = make_float4(0.f, 0.f, 0.f, 0.f);
            int gr = brow + r;
            if (gr < M) v = *(const float4*)(A + (size_t)gr * K + k0 + kc);
            As[kc + 0][r] = v.x; As[kc + 1][r] = v.y;
            As[kc + 2][r] = v.z; As[kc + 3][r] = v.w;
        }
#pragma unroll
        for (int i = 0; i < 2; ++i) {
            int idx = tid + i * 256;            // 512 float4 of B tile
            int kk  = idx >> 4;                 // 32 k-rows, 16 float4 per row
            int c   = (idx & 15) << 2;
            float4 v = *(const float4*)(B + (size_t)(k0 + kk) * NC + bcol + c);
            Bs[kk][c + 0] = v.x; Bs[kk][c + 1] = v.y;
            Bs[kk][c + 2] = v.z; Bs[kk][c + 3] = v.w;
        }
        __syncthreads();
#pragma unroll
        for (int kk = 0; kk < BK; ++kk) {
            float a[4], b[4];
#pragma unroll
            for (int i = 0; i < 4; ++i) a[i] = As[kk][ty * 4 + i];
#pragma unroll
            for (int j = 0; j < 4; ++j) b[j] = Bs[kk][tx * 4 + j];
#pragma unroll
            for (int i = 0; i < 4; ++i)
#pragma unroll
                for (int j = 0; j < 4; ++j)
                    acc[i][j] = fmaf(a[i], b[j], acc[i][j]);
        }
        __syncthreads();
    }
#pragma unroll
    for (int i = 0; i < 4; ++i) {
        int gr = brow + ty * 4 + i;
        if (gr < M) {
            float4 v = make_float4(acc[i][0], acc[i][1], acc[i][2], acc[i][3]);
            *(float4*)(C + (size_t)gr * NC + bcol + tx * 4) = v;
        }
    }
}

// ------------- per-(node,head) attention scores: el = h·al, er = h·ar -------------
__global__ __launch_bounds__(256) void attn_scores_kernel(const float* __restrict__ h,
                                                          const float* __restrict__ al,
                                                          const float* __restrict__ ar,
                                                          float* __restrict__ el,
                                                          float* __restrict__ er,
                                                          int total, int heads, int dh) {
    int idx = blockIdx.x * 256 + threadIdx.x;   // node*heads + head
    if (idx >= total) return;
    int hd = idx % heads;
    const float* hp = h + (size_t)idx * dh;
    float a = 0.f, c = 0.f;
    for (int d = 0; d < dh; ++d) {
        float hv = hp[d];
        a = fmaf(hv, al[hd * dh + d], a);
        c = fmaf(hv, ar[hd * dh + d], c);
    }
    el[idx] = a;
    er[idx] = c;
}

// ------------- layer-1 edge pass: acc[dst] += p*h1[src], s[dst] += p -------------
// 32 threads per edge (float4 per thread over 128 features), 8 edges per block.
__global__ __launch_bounds__(256) void edge_pass1_kernel(const int* __restrict__ src,
                                                         const int* __restrict__ dst,
                                                         const float* __restrict__ h1,
                                                         const float* __restrict__ el,
                                                         const float* __restrict__ er,
                                                         float* __restrict__ acc,
                                                         float* __restrict__ s) {
    int e = blockIdx.x * 8 + (threadIdx.x >> 5);
    if (e >= NEDGES) return;
    int lane = threadIdx.x & 31;
    int u = src[e], v = dst[e];
    int hd = lane >> 2;                          // 4 lanes per head
    float sc = el[u * HEADS + hd] + er[v * HEADS + hd];
    sc = sc > 0.f ? sc : SLOPE * sc;
    float p = expf(sc);
    float4 hv = *(const float4*)(h1 + (size_t)u * HID + lane * 4);
    float* ap = acc + (size_t)v * HID + lane * 4;
    atomicAdd(ap + 0, p * hv.x);
    atomicAdd(ap + 1, p * hv.y);
    atomicAdd(ap + 2, p * hv.z);
    atomicAdd(ap + 3, p * hv.w);
    if ((lane & 3) == 0) atomicAdd(s + (size_t)v * HEADS + hd, p);
}

// ------------- layer-1 normalize + bias + ELU(ELU(.)) (in place) -------------
__global__ __launch_bounds__(256) void norm1_kernel(float* __restrict__ acc,
                                                    const float* __restrict__ s,
                                                    const float* __restrict__ b) {
    int idx = blockIdx.x * 256 + threadIdx.x;
    if (idx >= NNODES * HID) return;
    int f = idx & (HID - 1);
    int node = idx >> 7;
    int hd = f >> 4;
    float sv = s[node * HEADS + hd];
    float v = acc[idx];
    v = (sv > 0.f) ? v / sv : 0.f;
    v += b[f];
    v = v > 0.f ? v : expm1f(v);   // inner ELU
    v = v > 0.f ? v : expm1f(v);   // outer ELU
    acc[idx] = v;
}

// ------------- layer-2 edge pass: out[dst] += p*h2[src], s2[dst] += p -------------
// 16 threads per edge (float4 over 64 features), 16 edges per block.
__global__ __launch_bounds__(256) void edge_pass2_kernel(const int* __restrict__ src,
                                                         const int* __restrict__ dst,
                                                         const float* __restrict__ h2,
                                                         const float* __restrict__ el,
                                                         const float* __restrict__ er,
                                                         float* __restrict__ out,
                                                         float* __restrict__ s2) {
    int e = blockIdx.x * 16 + (threadIdx.x >> 4);
    if (e >= NEDGES) return;
    int lane = threadIdx.x & 15;
    int u = src[e], v = dst[e];
    float sc = el[u] + er[v];
    sc = sc > 0.f ? sc : SLOPE * sc;
    float p = expf(sc);
    float4 hv = *(const float4*)(h2 + (size_t)u * NCLS + lane * 4);
    float* op = out + (size_t)v * NCLS + lane * 4;
    atomicAdd(op + 0, p * hv.x);
    atomicAdd(op + 1, p * hv.y);
    atomicAdd(op + 2, p * hv.z);
    atomicAdd(op + 3, p * hv.w);
    if (lane == 0) atomicAdd(s2 + v, p);
}

// ------------- layer-2 normalize + bias (in place on d_out) -------------
__global__ __launch_bounds__(256) void norm2_kernel(float* __restrict__ out,
                                                    const float* __restrict__ s2,
                                                    const float* __restrict__ b) {
    int idx = blockIdx.x * 256 + threadIdx.x;
    if (idx >= NNODES * NCLS) return;
    int f = idx & (NCLS - 1);
    int node = idx >> 6;
    float sv = s2[node];
    float v = out[idx];
    v = (sv > 0.f) ? v / sv : 0.f;
    v += b[f];
    out[idx] = v;
}

extern "C" void kernel_launch(void* const* d_in, const int* in_sizes, int n_in,
                              void* d_out, int out_size, void* d_ws, size_t ws_size,
                              hipStream_t stream) {
    const float* x   = (const float*)d_in[0];
    const int*   src = (const int*)d_in[1];
    const int*   dst = (const int*)d_in[2];
    const float* W1  = (const float*)d_in[3];
    const float* al1 = (const float*)d_in[4];
    const float* ar1 = (const float*)d_in[5];
    const float* b1  = (const float*)d_in[6];
    const float* W2  = (const float*)d_in[7];
    const float* al2 = (const float*)d_in[8];
    const float* ar2 = (const float*)d_in[9];
    const float* b2  = (const float*)d_in[10];
    float* out = (float*)d_out;

    // workspace layout (floats): h1[N*HID] | acc1[N*HID] | el[N*HEADS] | er[N*HEADS] | s[N*HEADS]
    float* h1   = (float*)d_ws;                         // reused as h2 (N*NCLS) later
    float* acc1 = h1 + (size_t)NNODES * HID;            // becomes hfeat in-place
    float* el   = acc1 + (size_t)NNODES * HID;          // reused as el2 (N)
    float* er   = el + (size_t)NNODES * HEADS;          // reused as er2 (N)
    float* s1   = er + (size_t)NNODES * HEADS;          // reused as s2 (N)

    // zero atomic accumulators + output
    hipMemsetAsync(acc1, 0, (size_t)NNODES * HID * sizeof(float), stream);
    hipMemsetAsync(s1, 0, (size_t)NNODES * HEADS * sizeof(float), stream);
    hipMemsetAsync(out, 0, (size_t)out_size * sizeof(float), stream);

    // ---- layer 1 ----
    dim3 g1((NNODES + BM - 1) / BM, HID / BN);
    sgemm_kernel<<<g1, 256, 0, stream>>>(x, W1, h1, NNODES, IN_DIM, HID);

    attn_scores_kernel<<<(NNODES * HEADS + 255) / 256, 256, 0, stream>>>(
        h1, al1, ar1, el, er, NNODES * HEADS, HEADS, DH);

    edge_pass1_kernel<<<(NEDGES + 7) / 8, 256, 0, stream>>>(src, dst, h1, el, er, acc1, s1);

    norm1_kernel<<<(NNODES * HID + 255) / 256, 256, 0, stream>>>(acc1, s1, b1);

    // ---- layer 2 ----
    dim3 g2((NNODES + BM - 1) / BM, NCLS / BN);
    sgemm_kernel<<<g2, 256, 0, stream>>>(acc1, W2, h1, NNODES, HID, NCLS);  // h2 -> h1 buffer

    attn_scores_kernel<<<(NNODES + 255) / 256, 256, 0, stream>>>(
        h1, al2, ar2, el, er, NNODES, 1, NCLS);

    hipMemsetAsync(s1, 0, (size_t)NNODES * sizeof(float), stream);  // s2

    edge_pass2_kernel<<<(NEDGES + 15) / 16, 256, 0, stream>>>(src, dst, h1, el, er, out, s1);

    norm2_kernel<<<(NNODES * NCLS + 255) / 256, 256, 0, stream>>>(out, s1, b2);
}

// Round 2
// 929.264 us; speedup vs baseline: 4.8205x; 4.8205x over previous
//
#include <hip/hip_runtime.h>
#include <cstdint>
#include <cstddef>

#define NNODES 100000
#define NEDGES 1600000
#define IN_DIM 256
#define HID 128
#define HEADS 8
#define DH 16
#define NCLS 64
#define SLOPE 0.2f

// ---------------- fp32 tiled GEMM: C[M,NC] = A[M,K] @ B[K,NC] ----------------
#define BM 64
#define BN 64
#define BK 32

__global__ __launch_bounds__(256) void sgemm_kernel(const float* __restrict__ A,
                                                    const float* __restrict__ B,
                                                    float* __restrict__ C,
                                                    int M, int K, int NC) {
    __shared__ float As[BK][BM];
    __shared__ float Bs[BK][BN + 4];
    const int brow = blockIdx.x * BM;
    const int bcol = blockIdx.y * BN;
    const int tid = threadIdx.x;
    const int tx = tid & 15;
    const int ty = tid >> 4;
    float acc[4][4] = {};

    for (int k0 = 0; k0 < K; k0 += BK) {
#pragma unroll
        for (int i = 0; i < 2; ++i) {
            int idx = tid + i * 256;
            int r   = idx >> 3;
            int kc  = (idx & 7) << 2;
            float4 v = make_float4(0.f, 0.f, 0.f, 0.f);
            int gr = brow + r;
            if (gr < M) v = *(const float4*)(A + (size_t)gr * K + k0 + kc);
            As[kc + 0][r] = v.x; As[kc + 1][r] = v.y;
            As[kc + 2][r] = v.z; As[kc + 3][r] = v.w;
        }
#pragma unroll
        for (int i = 0; i < 2; ++i) {
            int idx = tid + i * 256;
            int kk  = idx >> 4;
            int c   = (idx & 15) << 2;
            float4 v = *(const float4*)(B + (size_t)(k0 + kk) * NC + bcol + c);
            Bs[kk][c + 0] = v.x; Bs[kk][c + 1] = v.y;
            Bs[kk][c + 2] = v.z; Bs[kk][c + 3] = v.w;
        }
        __syncthreads();
#pragma unroll
        for (int kk = 0; kk < BK; ++kk) {
            float a[4], b[4];
#pragma unroll
            for (int i = 0; i < 4; ++i) a[i] = As[kk][ty * 4 + i];
#pragma unroll
            for (int j = 0; j < 4; ++j) b[j] = Bs[kk][tx * 4 + j];
#pragma unroll
            for (int i = 0; i < 4; ++i)
#pragma unroll
                for (int j = 0; j < 4; ++j)
                    acc[i][j] = fmaf(a[i], b[j], acc[i][j]);
        }
        __syncthreads();
    }
#pragma unroll
    for (int i = 0; i < 4; ++i) {
        int gr = brow + ty * 4 + i;
        if (gr < M) {
            float4 v = make_float4(acc[i][0], acc[i][1], acc[i][2], acc[i][3]);
            *(float4*)(C + (size_t)gr * NC + bcol + tx * 4) = v;
        }
    }
}

// ---------------- CSR build: histogram / scan / scatter ----------------
__global__ __launch_bounds__(256) void hist_kernel(const int* __restrict__ dst,
                                                   int* __restrict__ counts) {
    int e = blockIdx.x * 256 + threadIdx.x;
    if (e >= NEDGES) return;
    atomicAdd(&counts[dst[e]], 1);
}

// single-workgroup exclusive scan of counts[0..N-1] -> row_off[0..N]
__global__ __launch_bounds__(1024) void scan_kernel(const int* __restrict__ counts,
                                                    int* __restrict__ row_off) {
    __shared__ int lds_sums[16];
    const int tid = threadIdx.x;
    const int wid = tid >> 6;
    const int lane = tid & 63;
    int carry = 0;
    for (int base = 0; base < NNODES; base += 1024) {
        int i = base + tid;
        int v = (i < NNODES) ? counts[i] : 0;
        int x = v;
#pragma unroll
        for (int d = 1; d < 64; d <<= 1) {
            int y = __shfl_up(x, d, 64);
            if (lane >= d) x += y;
        }
        if (lane == 63) lds_sums[wid] = x;
        __syncthreads();
        if (tid < 16) {
            int s = lds_sums[tid];
#pragma unroll
            for (int d = 1; d < 16; d <<= 1) {
                int y = __shfl_up(s, d, 64);
                if (tid >= d) s += y;
            }
            lds_sums[tid] = s;
        }
        __syncthreads();
        int wave_off = (wid > 0) ? lds_sums[wid - 1] : 0;
        if (i < NNODES) row_off[i] = carry + wave_off + (x - v);
        carry += lds_sums[15];
        __syncthreads();
    }
    if (tid == 0) row_off[NNODES] = carry;
}

__global__ __launch_bounds__(256) void scatter_kernel(const int* __restrict__ src,
                                                      const int* __restrict__ dst,
                                                      const int* __restrict__ row_off,
                                                      int* __restrict__ cursor,
                                                      int* __restrict__ sorted_src) {
    int e = blockIdx.x * 256 + threadIdx.x;
    if (e >= NEDGES) return;
    int v = dst[e];
    int pos = row_off[v] + atomicAdd(&cursor[v], 1);
    sorted_src[pos] = src[e];
}

// ---------------- layer-1 attention scores ----------------
__global__ __launch_bounds__(256) void attn_scores_kernel(const float* __restrict__ h,
                                                          const float* __restrict__ al,
                                                          const float* __restrict__ ar,
                                                          float* __restrict__ el,
                                                          float* __restrict__ er) {
    int idx = blockIdx.x * 256 + threadIdx.x;   // node*HEADS + head
    if (idx >= NNODES * HEADS) return;
    int hd = idx & (HEADS - 1);
    const float* hp = h + (size_t)idx * DH;
    float a = 0.f, c = 0.f;
#pragma unroll
    for (int d = 0; d < DH; ++d) {
        float hv = hp[d];
        a = fmaf(hv, al[hd * DH + d], a);
        c = fmaf(hv, ar[hd * DH + d], c);
    }
    el[idx] = a;
    er[idx] = c;
}

// ---------------- layer-1 aggregation, fused: softmax-agg + bias + ELU^2 +
//                  (hf @ W2) + layer-2 attention scores ----------------
// 1 wave per node, grid-stride over nodes. Lane l owns features 2l,2l+1.
__global__ __launch_bounds__(256) void aggregate1_kernel(const float* __restrict__ h1,
                                                         const float* __restrict__ el1,
                                                         const float* __restrict__ er1,
                                                         const int* __restrict__ row_off,
                                                         const int* __restrict__ sorted_src,
                                                         const float* __restrict__ W2,
                                                         const float* __restrict__ al2,
                                                         const float* __restrict__ ar2,
                                                         const float* __restrict__ b1,
                                                         float* __restrict__ h2,
                                                         float* __restrict__ el2,
                                                         float* __restrict__ er2) {
    __shared__ float W2s[HID * NCLS];   // 32 KB
    __shared__ float al2s[NCLS], ar2s[NCLS], b1s[HID];
    const int tid = threadIdx.x;
    for (int i = tid; i < HID * NCLS; i += 256) W2s[i] = W2[i];
    if (tid < NCLS) { al2s[tid] = al2[tid]; ar2s[tid] = ar2[tid]; }
    if (tid < HID) b1s[tid] = b1[tid];
    __syncthreads();

    const int wid = tid >> 6;
    const int lane = tid & 63;
    const int hd = lane >> 3;                 // 8 lanes per head
    const int stride = gridDim.x * 4;

    for (int v = blockIdx.x * 4 + wid; v < NNODES; v += stride) {
        const int beg = row_off[v], end = row_off[v + 1];
        const float er_v = er1[v * HEADS + hd];
        float accx = 0.f, accy = 0.f, sp = 0.f;
        for (int j0 = beg; j0 < end; j0 += 64) {
            const int nj = min(64, end - j0);
            int us = (j0 + lane < end) ? sorted_src[j0 + lane] : 0;
            for (int j = 0; j < nj; ++j) {
                int u = __shfl(us, j, 64);
                float sc = el1[u * HEADS + hd] + er_v;
                sc = sc > 0.f ? sc : SLOPE * sc;
                float p = __expf(sc);
                float2 hv = *(const float2*)(h1 + (size_t)u * HID + lane * 2);
                accx = fmaf(p, hv.x, accx);
                accy = fmaf(p, hv.y, accy);
                sp += p;
            }
        }
        float inv = sp > 0.f ? 1.0f / sp : 0.f;
        float fx = accx * inv + b1s[lane * 2];
        float fy = accy * inv + b1s[lane * 2 + 1];
        fx = fx > 0.f ? fx : expm1f(fx);  fx = fx > 0.f ? fx : expm1f(fx);
        fy = fy > 0.f ? fy : expm1f(fy);  fy = fy > 0.f ? fy : expm1f(fy);

        // h2[v][lane] = sum_k hf[k] * W2[k][lane], hf distributed as (fx,fy) per lane
        float o = 0.f;
#pragma unroll
        for (int k = 0; k < 64; ++k) {
            float a = __shfl(fx, k, 64);
            float c = __shfl(fy, k, 64);
            o = fmaf(a, W2s[(2 * k) * NCLS + lane], o);
            o = fmaf(c, W2s[(2 * k + 1) * NCLS + lane], o);
        }
        h2[(size_t)v * NCLS + lane] = o;

        float pl = o * al2s[lane];
        float pr = o * ar2s[lane];
#pragma unroll
        for (int d = 32; d > 0; d >>= 1) {
            pl += __shfl_xor(pl, d, 64);
            pr += __shfl_xor(pr, d, 64);
        }
        if (lane == 0) { el2[v] = pl; er2[v] = pr; }
    }
}

// ---------------- layer-2 aggregation: softmax-agg + bias -> d_out ----------------
// 1 wave per node, lane = class.
__global__ __launch_bounds__(256) void aggregate2_kernel(const float* __restrict__ h2,
                                                         const float* __restrict__ el2,
                                                         const float* __restrict__ er2,
                                                         const int* __restrict__ row_off,
                                                         const int* __restrict__ sorted_src,
                                                         const float* __restrict__ b2,
                                                         float* __restrict__ out) {
    const int tid = threadIdx.x;
    const int v = blockIdx.x * 4 + (tid >> 6);
    if (v >= NNODES) return;
    const int lane = tid & 63;
    const int beg = row_off[v], end = row_off[v + 1];
    const float er_v = er2[v];
    float acc = 0.f, sp = 0.f;
    for (int j0 = beg; j0 < end; j0 += 64) {
        const int nj = min(64, end - j0);
        int idx = j0 + lane;
        bool valid = idx < end;
        int us = valid ? sorted_src[idx] : 0;
        float ev = valid ? el2[us] : 0.f;
        for (int j = 0; j < nj; ++j) {
            int u = __shfl(us, j, 64);
            float sc = __shfl(ev, j, 64) + er_v;
            sc = sc > 0.f ? sc : SLOPE * sc;
            float p = __expf(sc);
            float hv = h2[(size_t)u * NCLS + lane];
            acc = fmaf(p, hv, acc);
            sp += p;
        }
    }
    out[(size_t)v * NCLS + lane] = (sp > 0.f ? acc / sp : 0.f) + b2[lane];
}

extern "C" void kernel_launch(void* const* d_in, const int* in_sizes, int n_in,
                              void* d_out, int out_size, void* d_ws, size_t ws_size,
                              hipStream_t stream) {
    const float* x   = (const float*)d_in[0];
    const int*   src = (const int*)d_in[1];
    const int*   dst = (const int*)d_in[2];
    const float* W1  = (const float*)d_in[3];
    const float* al1 = (const float*)d_in[4];
    const float* ar1 = (const float*)d_in[5];
    const float* b1  = (const float*)d_in[6];
    const float* W2  = (const float*)d_in[7];
    const float* al2 = (const float*)d_in[8];
    const float* ar2 = (const float*)d_in[9];
    const float* b2  = (const float*)d_in[10];
    float* out = (float*)d_out;

    // workspace layout (4B slots), total ~91 MB
    float* h1  = (float*)d_ws;                          // N*HID   = 12.8M
    float* el1 = h1 + (size_t)NNODES * HID;             // N*HEADS = 0.8M
    float* er1 = el1 + (size_t)NNODES * HEADS;          // 0.8M
    float* h2  = er1 + (size_t)NNODES * HEADS;          // N*NCLS  = 6.4M
    float* el2 = h2 + (size_t)NNODES * NCLS;            // 0.1M
    float* er2 = el2 + NNODES;                          // 0.1M
    int* counts     = (int*)(er2 + NNODES);             // 0.1M (doubles as cursor)
    int* row_off    = counts + NNODES;                  // 0.1M
    int* sorted_src = row_off + (NNODES + 1);           // 1.6M

    // ---- CSR build (dst-sorted edge list, shared by both layers) ----
    hipMemsetAsync(counts, 0, NNODES * sizeof(int), stream);
    hist_kernel<<<(NEDGES + 255) / 256, 256, 0, stream>>>(dst, counts);
    scan_kernel<<<1, 1024, 0, stream>>>(counts, row_off);
    hipMemsetAsync(counts, 0, NNODES * sizeof(int), stream);
    scatter_kernel<<<(NEDGES + 255) / 256, 256, 0, stream>>>(src, dst, row_off, counts, sorted_src);

    // ---- layer 1 ----
    dim3 g1((NNODES + BM - 1) / BM, HID / BN);
    sgemm_kernel<<<g1, 256, 0, stream>>>(x, W1, h1, NNODES, IN_DIM, HID);

    attn_scores_kernel<<<(NNODES * HEADS + 255) / 256, 256, 0, stream>>>(h1, al1, ar1, el1, er1);

    aggregate1_kernel<<<2048, 256, 0, stream>>>(h1, el1, er1, row_off, sorted_src,
                                                W2, al2, ar2, b1, h2, el2, er2);

    // ---- layer 2 ----
    aggregate2_kernel<<<(NNODES + 3) / 4, 256, 0, stream>>>(h2, el2, er2, row_off, sorted_src,
                                                            b2, out);
}

// Round 6
// 700.915 us; speedup vs baseline: 6.3909x; 1.3258x over previous
//
#include <hip/hip_runtime.h>
#include <cstdint>
#include <cstddef>

#define NNODES 100000
#define NEDGES 1600000
#define IN_DIM 256
#define HID 128
#define HEADS 8
#define DH 16
#define NCLS 64
#define SLOPE 0.2f

// ---------------- fp32 tiled GEMM: C[M,NC] = A[M,K] @ B[K,NC] ----------------
#define BM 64
#define BN 64
#define BK 32

__global__ __launch_bounds__(256) void sgemm_kernel(const float* __restrict__ A,
                                                    const float* __restrict__ B,
                                                    float* __restrict__ C,
                                                    int M, int K, int NC) {
    __shared__ float As[BK][BM];
    __shared__ float Bs[BK][BN + 4];
    const int brow = blockIdx.x * BM;
    const int bcol = blockIdx.y * BN;
    const int tid = threadIdx.x;
    const int tx = tid & 15;
    const int ty = tid >> 4;
    float acc[4][4] = {};

    for (int k0 = 0; k0 < K; k0 += BK) {
#pragma unroll
        for (int i = 0; i < 2; ++i) {
            int idx = tid + i * 256;
            int r   = idx >> 3;
            int kc  = (idx & 7) << 2;
            float4 v = make_float4(0.f, 0.f, 0.f, 0.f);
            int gr = brow + r;
            if (gr < M) v = *(const float4*)(A + (size_t)gr * K + k0 + kc);
            As[kc + 0][r] = v.x; As[kc + 1][r] = v.y;
            As[kc + 2][r] = v.z; As[kc + 3][r] = v.w;
        }
#pragma unroll
        for (int i = 0; i < 2; ++i) {
            int idx = tid + i * 256;
            int kk  = idx >> 4;
            int c   = (idx & 15) << 2;
            float4 v = *(const float4*)(B + (size_t)(k0 + kk) * NC + bcol + c);
            Bs[kk][c + 0] = v.x; Bs[kk][c + 1] = v.y;
            Bs[kk][c + 2] = v.z; Bs[kk][c + 3] = v.w;
        }
        __syncthreads();
#pragma unroll
        for (int kk = 0; kk < BK; ++kk) {
            float a[4], b[4];
#pragma unroll
            for (int i = 0; i < 4; ++i) a[i] = As[kk][ty * 4 + i];
#pragma unroll
            for (int j = 0; j < 4; ++j) b[j] = Bs[kk][tx * 4 + j];
#pragma unroll
            for (int i = 0; i < 4; ++i)
#pragma unroll
                for (int j = 0; j < 4; ++j)
                    acc[i][j] = fmaf(a[i], b[j], acc[i][j]);
        }
        __syncthreads();
    }
#pragma unroll
    for (int i = 0; i < 4; ++i) {
        int gr = brow + ty * 4 + i;
        if (gr < M) {
            float4 v = make_float4(acc[i][0], acc[i][1], acc[i][2], acc[i][3]);
            *(float4*)(C + (size_t)gr * NC + bcol + tx * 4) = v;
        }
    }
}

// ---------------- CSR build ----------------
__global__ __launch_bounds__(256) void hist_kernel(const int* __restrict__ dst,
                                                   int* __restrict__ counts) {
    int e = blockIdx.x * 256 + threadIdx.x;
    if (e >= NEDGES) return;
    atomicAdd(&counts[dst[e]], 1);
}

// phase 1: per-1024-chunk sums
__global__ __launch_bounds__(256) void scan_partial_kernel(const int* __restrict__ counts,
                                                           int* __restrict__ partials) {
    __shared__ int ws[4];
    const int t = threadIdx.x, lane = t & 63, wid = t >> 6;
    int base = blockIdx.x * 1024 + t * 4;
    int s = 0;
    if (base < NNODES) {
        int4 c = *(const int4*)(counts + base);
        s = c.x + c.y + c.z + c.w;
    }
#pragma unroll
    for (int d = 1; d < 64; d <<= 1) s += __shfl_xor(s, d, 64);
    if (lane == 0) ws[wid] = s;
    __syncthreads();
    if (t == 0) partials[blockIdx.x] = ws[0] + ws[1] + ws[2] + ws[3];
}

// phase 2: exclusive scan of the partials, single block
__global__ __launch_bounds__(128) void scan_root_kernel(int* __restrict__ partials, int nblk) {
    __shared__ int buf[128];
    const int t = threadIdx.x;
    buf[t] = (t < nblk) ? partials[t] : 0;
    __syncthreads();
#pragma unroll
    for (int d = 1; d < 128; d <<= 1) {
        int v = (t >= d) ? buf[t - d] : 0;
        __syncthreads();
        buf[t] += v;
        __syncthreads();
    }
    if (t < nblk) partials[t] = (t == 0) ? 0 : buf[t - 1];
}

// phase 3: per-element exclusive scan + block offset
__global__ __launch_bounds__(256) void scan_final_kernel(const int* __restrict__ counts,
                                                         const int* __restrict__ partials,
                                                         int* __restrict__ row_off) {
    __shared__ int ws[4];
    const int t = threadIdx.x, lane = t & 63, wid = t >> 6;
    int base = blockIdx.x * 1024 + t * 4;
    int4 c = {0, 0, 0, 0};
    if (base < NNODES) c = *(const int4*)(counts + base);
    int s0 = c.x, s01 = c.x + c.y, s012 = s01 + c.z, ts = s012 + c.w;
    int x = ts;
#pragma unroll
    for (int d = 1; d < 64; d <<= 1) {
        int y = __shfl_up(x, d, 64);
        if (lane >= d) x += y;
    }
    if (lane == 63) ws[wid] = x;
    __syncthreads();
    int woff = 0;
#pragma unroll
    for (int i = 0; i < 4; ++i) if (i < wid) woff += ws[i];
    int excl = partials[blockIdx.x] + woff + (x - ts);
    if (base < NNODES) {
        row_off[base + 0] = excl;
        row_off[base + 1] = excl + s0;
        row_off[base + 2] = excl + s01;
        row_off[base + 3] = excl + s012;
    }
    if (blockIdx.x == 0 && t == 0) row_off[NNODES] = NEDGES;
}

__global__ __launch_bounds__(256) void scatter_kernel(const int* __restrict__ src,
                                                      const int* __restrict__ dst,
                                                      const int* __restrict__ row_off,
                                                      int* __restrict__ cursor,
                                                      int* __restrict__ sorted_src) {
    int e = blockIdx.x * 256 + threadIdx.x;
    if (e >= NEDGES) return;
    int v = dst[e];
    int pos = row_off[v] + atomicAdd(&cursor[v], 1);
    sorted_src[pos] = src[e];
}

// ---------------- layer-1 attention scores ----------------
__global__ __launch_bounds__(256) void attn_scores_kernel(const float* __restrict__ h,
                                                          const float* __restrict__ al,
                                                          const float* __restrict__ ar,
                                                          float* __restrict__ el,
                                                          float* __restrict__ er) {
    int idx = blockIdx.x * 256 + threadIdx.x;   // node*HEADS + head
    if (idx >= NNODES * HEADS) return;
    int hd = idx & (HEADS - 1);
    const float* hp = h + (size_t)idx * DH;
    float a = 0.f, c = 0.f;
#pragma unroll
    for (int d = 0; d < DH; ++d) {
        float hv = hp[d];
        a = fmaf(hv, al[hd * DH + d], a);
        c = fmaf(hv, ar[hd * DH + d], c);
    }
    el[idx] = a;
    er[idx] = c;
}

// ---------------- layer-1 aggregation (4 edge-groups/wave, UNIFORM loop) +
//                  fused epilogue via shfl broadcast ----------------
__global__ __launch_bounds__(256) void aggregate1_kernel(const float* __restrict__ h1,
                                                         const float* __restrict__ el1,
                                                         const float* __restrict__ er1,
                                                         const int* __restrict__ row_off,
                                                         const int* __restrict__ sorted_src,
                                                         const float* __restrict__ W2,
                                                         const float* __restrict__ al2,
                                                         const float* __restrict__ ar2,
                                                         const float* __restrict__ b1,
                                                         float* __restrict__ h2,
                                                         float* __restrict__ el2,
                                                         float* __restrict__ er2) {
    __shared__ float W2s[HID * NCLS];   // 32 KB
    __shared__ float al2s[NCLS], ar2s[NCLS], b1s[HID];
    const int tid = threadIdx.x;
    for (int i = tid; i < HID * NCLS; i += 256) W2s[i] = W2[i];
    if (tid < NCLS) { al2s[tid] = al2[tid]; ar2s[tid] = ar2[tid]; }
    if (tid < HID) b1s[tid] = b1[tid];
    __syncthreads();

    const int wid = tid >> 6, lane = tid & 63;
    const int g = lane >> 4, sub = lane & 15, hd = sub >> 1;

    for (int v = blockIdx.x * 4 + wid; v < NNODES; v += gridDim.x * 4) {
        const int beg = row_off[v], end = row_off[v + 1];
        const float er_v = er1[v * HEADS + hd];
        float4 a0 = {0,0,0,0}, a1 = {0,0,0,0};
        float sp = 0.f;
        for (int j0 = beg; j0 < end; j0 += 64) {
            const int nj = min(64, end - j0);
            const int nit = (nj + 3) >> 2;     // wave-uniform trip count
            int us = (j0 + lane < end) ? sorted_src[j0 + lane] : 0;
            for (int i = 0; i < nit; ++i) {
                int j = g + 4 * i;              // 0..63; may be >= nj (predicated)
                int u = __shfl(us, j, 64);      // source lane always active
                float sc = el1[u * HEADS + hd] + er_v;
                sc = sc > 0.f ? sc : SLOPE * sc;
                float p = (j < nj) ? __expf(sc) : 0.f;
                const float4* hp = (const float4*)(h1 + (size_t)u * HID + sub * 8);
                float4 h0 = hp[0], h1v = hp[1];
                a0.x = fmaf(p, h0.x, a0.x);  a0.y = fmaf(p, h0.y, a0.y);
                a0.z = fmaf(p, h0.z, a0.z);  a0.w = fmaf(p, h0.w, a0.w);
                a1.x = fmaf(p, h1v.x, a1.x); a1.y = fmaf(p, h1v.y, a1.y);
                a1.z = fmaf(p, h1v.z, a1.z); a1.w = fmaf(p, h1v.w, a1.w);
                sp += p;
            }
        }
        // combine the 4 edge-groups (lane ^16/^32 keeps sub, hence head)
#pragma unroll
        for (int d = 16; d <= 32; d <<= 1) {
            a0.x += __shfl_xor(a0.x, d, 64); a0.y += __shfl_xor(a0.y, d, 64);
            a0.z += __shfl_xor(a0.z, d, 64); a0.w += __shfl_xor(a0.w, d, 64);
            a1.x += __shfl_xor(a1.x, d, 64); a1.y += __shfl_xor(a1.y, d, 64);
            a1.z += __shfl_xor(a1.z, d, 64); a1.w += __shfl_xor(a1.w, d, 64);
            sp += __shfl_xor(sp, d, 64);
        }
        float inv = sp > 0.f ? 1.0f / sp : 0.f;
        float f[8] = {a0.x, a0.y, a0.z, a0.w, a1.x, a1.y, a1.z, a1.w};
#pragma unroll
        for (int i = 0; i < 8; ++i) {
            float t = f[i] * inv + b1s[sub * 8 + i];
            t = t > 0.f ? t : expm1f(t);
            t = t > 0.f ? t : expm1f(t);
            f[i] = t;
        }
        // epilogue GEMM via shfl broadcast: hf[s*8+i] lives in lane s (sub==s)
        float o = 0.f;
#pragma unroll
        for (int s = 0; s < 16; ++s) {
#pragma unroll
            for (int i = 0; i < 8; ++i) {
                float hf = __shfl(f[i], s, 64);
                o = fmaf(hf, W2s[(s * 8 + i) * NCLS + lane], o);
            }
        }
        h2[(size_t)v * NCLS + lane] = o;
        float pl = o * al2s[lane], pr = o * ar2s[lane];
#pragma unroll
        for (int d = 32; d > 0; d >>= 1) {
            pl += __shfl_xor(pl, d, 64);
            pr += __shfl_xor(pr, d, 64);
        }
        if (lane == 0) { el2[v] = pl; er2[v] = pr; }
    }
}

// ---------------- layer-2 aggregation (4 edge-groups/wave, UNIFORM loop) -> d_out ----------------
__global__ __launch_bounds__(256) void aggregate2_kernel(const float* __restrict__ h2,
                                                         const float* __restrict__ el2,
                                                         const float* __restrict__ er2,
                                                         const int* __restrict__ row_off,
                                                         const int* __restrict__ sorted_src,
                                                         const float* __restrict__ b2,
                                                         float* __restrict__ out) {
    const int tid = threadIdx.x;
    const int v = blockIdx.x * 4 + (tid >> 6);
    if (v >= NNODES) return;
    const int lane = tid & 63, g = lane >> 4, sub = lane & 15;
    const int beg = row_off[v], end = row_off[v + 1];
    const float er_v = er2[v];
    float4 acc = {0,0,0,0};
    float sp = 0.f;
    for (int j0 = beg; j0 < end; j0 += 64) {
        const int nj = min(64, end - j0);
        const int nit = (nj + 3) >> 2;
        bool valid = j0 + lane < end;
        int us = valid ? sorted_src[j0 + lane] : 0;
        float ev = valid ? el2[us] : 0.f;
        for (int i = 0; i < nit; ++i) {
            int j = g + 4 * i;
            int u = __shfl(us, j, 64);
            float sc = __shfl(ev, j, 64) + er_v;
            sc = sc > 0.f ? sc : SLOPE * sc;
            float p = (j < nj) ? __expf(sc) : 0.f;
            float4 hv = *(const float4*)(h2 + (size_t)u * NCLS + sub * 4);
            acc.x = fmaf(p, hv.x, acc.x); acc.y = fmaf(p, hv.y, acc.y);
            acc.z = fmaf(p, hv.z, acc.z); acc.w = fmaf(p, hv.w, acc.w);
            sp += p;
        }
    }
#pragma unroll
    for (int d = 16; d <= 32; d <<= 1) {
        acc.x += __shfl_xor(acc.x, d, 64); acc.y += __shfl_xor(acc.y, d, 64);
        acc.z += __shfl_xor(acc.z, d, 64); acc.w += __shfl_xor(acc.w, d, 64);
        sp += __shfl_xor(sp, d, 64);
    }
    if (g == 0) {
        float inv = sp > 0.f ? 1.0f / sp : 0.f;
        float4 bb = *(const float4*)(b2 + sub * 4);
        float4 o;
        o.x = acc.x * inv + bb.x; o.y = acc.y * inv + bb.y;
        o.z = acc.z * inv + bb.z; o.w = acc.w * inv + bb.w;
        *(float4*)(out + (size_t)v * NCLS + sub * 4) = o;
    }
}

extern "C" void kernel_launch(void* const* d_in, const int* in_sizes, int n_in,
                              void* d_out, int out_size, void* d_ws, size_t ws_size,
                              hipStream_t stream) {
    const float* x   = (const float*)d_in[0];
    const int*   src = (const int*)d_in[1];
    const int*   dst = (const int*)d_in[2];
    const float* W1  = (const float*)d_in[3];
    const float* al1 = (const float*)d_in[4];
    const float* ar1 = (const float*)d_in[5];
    const float* b1  = (const float*)d_in[6];
    const float* W2  = (const float*)d_in[7];
    const float* al2 = (const float*)d_in[8];
    const float* ar2 = (const float*)d_in[9];
    const float* b2  = (const float*)d_in[10];
    float* out = (float*)d_out;

    // workspace layout (float slots), ~91 MB total
    float* h1  = (float*)d_ws;                          // N*HID
    float* el1 = h1 + (size_t)NNODES * HID;
    float* er1 = el1 + (size_t)NNODES * HEADS;
    float* h2  = er1 + (size_t)NNODES * HEADS;          // N*NCLS
    float* el2 = h2 + (size_t)NNODES * NCLS;
    float* er2 = el2 + NNODES;
    int* counts     = (int*)(er2 + NNODES);
    int* row_off    = counts + NNODES;
    int* sorted_src = row_off + (NNODES + 1);
    int* partials   = sorted_src + NEDGES;              // 128 ints

    const int nscan = (NNODES + 1023) / 1024;           // 98

    // ---- CSR build ----
    hipMemsetAsync(counts, 0, NNODES * sizeof(int), stream);
    hist_kernel<<<(NEDGES + 255) / 256, 256, 0, stream>>>(dst, counts);
    scan_partial_kernel<<<nscan, 256, 0, stream>>>(counts, partials);
    scan_root_kernel<<<1, 128, 0, stream>>>(partials, nscan);
    scan_final_kernel<<<nscan, 256, 0, stream>>>(counts, partials, row_off);
    hipMemsetAsync(counts, 0, NNODES * sizeof(int), stream);
    scatter_kernel<<<(NEDGES + 255) / 256, 256, 0, stream>>>(src, dst, row_off, counts, sorted_src);

    // ---- layer 1 ----
    dim3 g1((NNODES + BM - 1) / BM, HID / BN);
    sgemm_kernel<<<g1, 256, 0, stream>>>(x, W1, h1, NNODES, IN_DIM, HID);
    attn_scores_kernel<<<(NNODES * HEADS + 255) / 256, 256, 0, stream>>>(h1, al1, ar1, el1, er1);
    aggregate1_kernel<<<2048, 256, 0, stream>>>(h1, el1, er1, row_off, sorted_src,
                                                W2, al2, ar2, b1, h2, el2, er2);

    // ---- layer 2 ----
    aggregate2_kernel<<<(NNODES + 3) / 4, 256, 0, stream>>>(h2, el2, er2, row_off, sorted_src,
                                                            b2, out);
}

// Round 7
// 554.757 us; speedup vs baseline: 8.0747x; 1.2635x over previous
//
#include <hip/hip_runtime.h>
#include <cstdint>
#include <cstddef>

#define NNODES 100000
#define NEDGES 1600000
#define IN_DIM 256
#define HID 128
#define HEADS 8
#define DH 16
#define NCLS 64
#define SLOPE 0.2f

typedef __attribute__((ext_vector_type(8))) short bf16x8;
typedef __attribute__((ext_vector_type(4))) float f32x4;

// float -> bf16 (round-to-nearest-even; inputs finite)
static __device__ __forceinline__ unsigned short f2bf(float f) {
    union { float f; uint32_t u; } c;
    c.f = f;
    uint32_t r = (c.u + 0x7FFFu + ((c.u >> 16) & 1u)) >> 16;
    return (unsigned short)r;
}
static __device__ __forceinline__ float bflo(unsigned int w) {
    union { uint32_t u; float f; } c; c.u = w << 16; return c.f;
}
static __device__ __forceinline__ float bfhi(unsigned int w) {
    union { uint32_t u; float f; } c; c.u = w & 0xFFFF0000u; return c.f;
}

// ---------------- W1 -> W1T bf16 [HID][IN_DIM] ----------------
__global__ __launch_bounds__(256) void prep_w1t_kernel(const float* __restrict__ W1,
                                                       short* __restrict__ W1T) {
    int idx = blockIdx.x * 256 + threadIdx.x;   // over IN_DIM*HID
    if (idx >= IN_DIM * HID) return;
    int k = idx >> 7;          // 0..255
    int n = idx & 127;         // 0..127
    W1T[n * IN_DIM + k] = (short)f2bf(W1[idx]);
}

// ---------------- bf16 MFMA GEMM: h1b[M,128](bf16) = x[M,256] @ W1 ----------------
// 128x128 block tile, 4 waves 2x2, 16x16x32 mfma, A staged f32->bf16 in LDS,
// B-frags direct from W1T (L2-resident 64KB).
__global__ __launch_bounds__(256) void gemm1_kernel(const float* __restrict__ x,
                                                    const short* __restrict__ W1T,
                                                    unsigned short* __restrict__ h1b) {
    __shared__ short Asl[128 * 40];   // row stride 40 shorts (80B)
    const int tid = threadIdx.x;
    const int brow = blockIdx.x * 128;
    const int wid = tid >> 6, lane = tid & 63;
    const int wm = (wid >> 1) * 64, wn = (wid & 1) * 64;
    const int mr = lane & 15;        // A row / B col / D col
    const int ks = lane >> 4;        // k-slot (8 bf16)
    const int sr = tid >> 1;         // staging row
    const int sch = tid & 1;         // staging chunk
    const int grow = brow + sr;

    f32x4 acc[4][4];
#pragma unroll
    for (int i = 0; i < 4; ++i)
#pragma unroll
        for (int j = 0; j < 4; ++j) acc[i][j] = (f32x4){0.f, 0.f, 0.f, 0.f};

    for (int k0 = 0; k0 < IN_DIM; k0 += 32) {
        float4 v0 = {0,0,0,0}, v1 = {0,0,0,0}, v2 = {0,0,0,0}, v3 = {0,0,0,0};
        if (grow < NNODES) {
            const float* xp = x + (size_t)grow * IN_DIM + k0 + sch * 16;
            v0 = *(const float4*)(xp + 0);
            v1 = *(const float4*)(xp + 4);
            v2 = *(const float4*)(xp + 8);
            v3 = *(const float4*)(xp + 12);
        }
        bf16x8 p0, p1;
        p0[0] = (short)f2bf(v0.x); p0[1] = (short)f2bf(v0.y);
        p0[2] = (short)f2bf(v0.z); p0[3] = (short)f2bf(v0.w);
        p0[4] = (short)f2bf(v1.x); p0[5] = (short)f2bf(v1.y);
        p0[6] = (short)f2bf(v1.z); p0[7] = (short)f2bf(v1.w);
        p1[0] = (short)f2bf(v2.x); p1[1] = (short)f2bf(v2.y);
        p1[2] = (short)f2bf(v2.z); p1[3] = (short)f2bf(v2.w);
        p1[4] = (short)f2bf(v3.x); p1[5] = (short)f2bf(v3.y);
        p1[6] = (short)f2bf(v3.z); p1[7] = (short)f2bf(v3.w);
        __syncthreads();
        *(bf16x8*)(Asl + sr * 40 + sch * 16 + 0) = p0;
        *(bf16x8*)(Asl + sr * 40 + sch * 16 + 8) = p1;
        __syncthreads();

        bf16x8 af[4], bfr[4];
#pragma unroll
        for (int i = 0; i < 4; ++i)
            af[i] = *(const bf16x8*)(Asl + (wm + i * 16 + mr) * 40 + ks * 8);
#pragma unroll
        for (int j = 0; j < 4; ++j)
            bfr[j] = *(const bf16x8*)(W1T + (size_t)(wn + j * 16 + mr) * IN_DIM + k0 + ks * 8);
#pragma unroll
        for (int i = 0; i < 4; ++i)
#pragma unroll
            for (int j = 0; j < 4; ++j)
                acc[i][j] = __builtin_amdgcn_mfma_f32_16x16x32_bf16(af[i], bfr[j], acc[i][j], 0, 0, 0);
    }

    // D layout: col = lane&15, row = (lane>>4)*4 + reg
#pragma unroll
    for (int i = 0; i < 4; ++i) {
#pragma unroll
        for (int j = 0; j < 4; ++j) {
            int col = wn + j * 16 + mr;
#pragma unroll
            for (int r = 0; r < 4; ++r) {
                int row = brow + wm + i * 16 + ks * 4 + r;
                if (row < NNODES) h1b[(size_t)row * HID + col] = f2bf(acc[i][j][r]);
            }
        }
    }
}

// ---------------- CSR build ----------------
__global__ __launch_bounds__(256) void hist_kernel(const int* __restrict__ dst,
                                                   int* __restrict__ counts) {
    int e = blockIdx.x * 256 + threadIdx.x;
    if (e >= NEDGES) return;
    atomicAdd(&counts[dst[e]], 1);
}

__global__ __launch_bounds__(256) void scan_partial_kernel(const int* __restrict__ counts,
                                                           int* __restrict__ partials) {
    __shared__ int ws[4];
    const int t = threadIdx.x, lane = t & 63, wid = t >> 6;
    int base = blockIdx.x * 1024 + t * 4;
    int s = 0;
    if (base < NNODES) {
        int4 c = *(const int4*)(counts + base);
        s = c.x + c.y + c.z + c.w;
    }
#pragma unroll
    for (int d = 1; d < 64; d <<= 1) s += __shfl_xor(s, d, 64);
    if (lane == 0) ws[wid] = s;
    __syncthreads();
    if (t == 0) partials[blockIdx.x] = ws[0] + ws[1] + ws[2] + ws[3];
}

__global__ __launch_bounds__(128) void scan_root_kernel(int* __restrict__ partials, int nblk) {
    __shared__ int buf[128];
    const int t = threadIdx.x;
    buf[t] = (t < nblk) ? partials[t] : 0;
    __syncthreads();
#pragma unroll
    for (int d = 1; d < 128; d <<= 1) {
        int v = (t >= d) ? buf[t - d] : 0;
        __syncthreads();
        buf[t] += v;
        __syncthreads();
    }
    if (t < nblk) partials[t] = (t == 0) ? 0 : buf[t - 1];
}

__global__ __launch_bounds__(256) void scan_final_kernel(const int* __restrict__ counts,
                                                         const int* __restrict__ partials,
                                                         int* __restrict__ row_off) {
    __shared__ int ws[4];
    const int t = threadIdx.x, lane = t & 63, wid = t >> 6;
    int base = blockIdx.x * 1024 + t * 4;
    int4 c = {0, 0, 0, 0};
    if (base < NNODES) c = *(const int4*)(counts + base);
    int s0 = c.x, s01 = c.x + c.y, s012 = s01 + c.z, ts = s012 + c.w;
    int x = ts;
#pragma unroll
    for (int d = 1; d < 64; d <<= 1) {
        int y = __shfl_up(x, d, 64);
        if (lane >= d) x += y;
    }
    if (lane == 63) ws[wid] = x;
    __syncthreads();
    int woff = 0;
#pragma unroll
    for (int i = 0; i < 4; ++i) if (i < wid) woff += ws[i];
    int excl = partials[blockIdx.x] + woff + (x - ts);
    if (base < NNODES) {
        row_off[base + 0] = excl;
        row_off[base + 1] = excl + s0;
        row_off[base + 2] = excl + s01;
        row_off[base + 3] = excl + s012;
    }
    if (blockIdx.x == 0 && t == 0) row_off[NNODES] = NEDGES;
}

__global__ __launch_bounds__(256) void scatter_kernel(const int* __restrict__ src,
                                                      const int* __restrict__ dst,
                                                      const int* __restrict__ row_off,
                                                      int* __restrict__ cursor,
                                                      int* __restrict__ sorted_src) {
    int e = blockIdx.x * 256 + threadIdx.x;
    if (e >= NEDGES) return;
    int v = dst[e];
    int pos = row_off[v] + atomicAdd(&cursor[v], 1);
    sorted_src[pos] = src[e];
}

// ---------------- layer-1 attention scores (bf16 h1 in) ----------------
__global__ __launch_bounds__(256) void attn_scores_kernel(const unsigned short* __restrict__ h1b,
                                                          const float* __restrict__ al,
                                                          const float* __restrict__ ar,
                                                          float* __restrict__ el,
                                                          float* __restrict__ er) {
    int idx = blockIdx.x * 256 + threadIdx.x;   // node*HEADS + head
    if (idx >= NNODES * HEADS) return;
    int hd = idx & (HEADS - 1);
    const uint4* hp = (const uint4*)(h1b + (size_t)idx * DH);
    uint4 A = hp[0], B = hp[1];
    unsigned int w[8] = {A.x, A.y, A.z, A.w, B.x, B.y, B.z, B.w};
    float a = 0.f, c = 0.f;
#pragma unroll
    for (int i = 0; i < 8; ++i) {
        float lo = bflo(w[i]), hi = bfhi(w[i]);
        a = fmaf(lo, al[hd * DH + 2 * i], a);
        a = fmaf(hi, al[hd * DH + 2 * i + 1], a);
        c = fmaf(lo, ar[hd * DH + 2 * i], c);
        c = fmaf(hi, ar[hd * DH + 2 * i + 1], c);
    }
    el[idx] = a;
    er[idx] = c;
}

// ---------------- layer-1 aggregation: 4 edge-groups/wave, batch-4 gathers,
//                  fused bias+ELU^2 + (hf@W2) + layer-2 scores ----------------
__global__ __launch_bounds__(256) void aggregate1_kernel(const unsigned short* __restrict__ h1b,
                                                         const float* __restrict__ el1,
                                                         const float* __restrict__ er1,
                                                         const int* __restrict__ row_off,
                                                         const int* __restrict__ sorted_src,
                                                         const float* __restrict__ W2,
                                                         const float* __restrict__ al2,
                                                         const float* __restrict__ ar2,
                                                         const float* __restrict__ b1,
                                                         float* __restrict__ h2,
                                                         float* __restrict__ el2,
                                                         float* __restrict__ er2) {
    __shared__ float W2s[HID * NCLS];   // 32 KB
    __shared__ float al2s[NCLS], ar2s[NCLS], b1s[HID];
    const int tid = threadIdx.x;
    for (int i = tid; i < HID * NCLS; i += 256) W2s[i] = W2[i];
    if (tid < NCLS) { al2s[tid] = al2[tid]; ar2s[tid] = ar2[tid]; }
    if (tid < HID) b1s[tid] = b1[tid];
    __syncthreads();

    const int wid = tid >> 6, lane = tid & 63;
    const int g = lane >> 4, sub = lane & 15, hd = sub >> 1;

    for (int v = blockIdx.x * 4 + wid; v < NNODES; v += gridDim.x * 4) {
        const int beg = row_off[v], end = row_off[v + 1];
        const float er_v = er1[v * HEADS + hd];
        float a[8] = {0.f, 0.f, 0.f, 0.f, 0.f, 0.f, 0.f, 0.f};
        float sp = 0.f;
        for (int j0 = beg; j0 < end; j0 += 64) {
            const int nj = min(64, end - j0);
            const int nit = (nj + 3) >> 2;     // wave-uniform
            int us = (j0 + lane < end) ? sorted_src[j0 + lane] : 0;
            for (int ib = 0; ib < nit; ib += 4) {
                // batch 4 edges per group: compute indices, issue ALL loads first
                int j0i = g + 4 * (ib + 0), j1i = g + 4 * (ib + 1);
                int j2i = g + 4 * (ib + 2), j3i = g + 4 * (ib + 3);
                int u0 = __shfl(us, j0i & 63, 64);
                int u1 = __shfl(us, j1i & 63, 64);
                int u2 = __shfl(us, j2i & 63, 64);
                int u3 = __shfl(us, j3i & 63, 64);
                uint4 w0 = *(const uint4*)(h1b + (size_t)u0 * HID + sub * 8);
                uint4 w1 = *(const uint4*)(h1b + (size_t)u1 * HID + sub * 8);
                uint4 w2 = *(const uint4*)(h1b + (size_t)u2 * HID + sub * 8);
                uint4 w3 = *(const uint4*)(h1b + (size_t)u3 * HID + sub * 8);
                float e0 = el1[u0 * HEADS + hd], e1 = el1[u1 * HEADS + hd];
                float e2 = el1[u2 * HEADS + hd], e3 = el1[u3 * HEADS + hd];
                float s0 = e0 + er_v; s0 = s0 > 0.f ? s0 : SLOPE * s0;
                float s1 = e1 + er_v; s1 = s1 > 0.f ? s1 : SLOPE * s1;
                float s2 = e2 + er_v; s2 = s2 > 0.f ? s2 : SLOPE * s2;
                float s3 = e3 + er_v; s3 = s3 > 0.f ? s3 : SLOPE * s3;
                float p0 = (j0i < nj) ? __expf(s0) : 0.f;
                float p1 = (j1i < nj) ? __expf(s1) : 0.f;
                float p2 = (j2i < nj) ? __expf(s2) : 0.f;
                float p3 = (j3i < nj) ? __expf(s3) : 0.f;
                sp += p0 + p1 + p2 + p3;
#define ACC8(P, W) \
                a[0] = fmaf(P, bflo(W.x), a[0]); a[1] = fmaf(P, bfhi(W.x), a[1]); \
                a[2] = fmaf(P, bflo(W.y), a[2]); a[3] = fmaf(P, bfhi(W.y), a[3]); \
                a[4] = fmaf(P, bflo(W.z), a[4]); a[5] = fmaf(P, bfhi(W.z), a[5]); \
                a[6] = fmaf(P, bflo(W.w), a[6]); a[7] = fmaf(P, bfhi(W.w), a[7]);
                ACC8(p0, w0) ACC8(p1, w1) ACC8(p2, w2) ACC8(p3, w3)
#undef ACC8
            }
        }
        // combine the 4 edge-groups (lane ^16/^32 keeps sub, hence head)
#pragma unroll
        for (int d = 16; d <= 32; d <<= 1) {
#pragma unroll
            for (int i = 0; i < 8; ++i) a[i] += __shfl_xor(a[i], d, 64);
            sp += __shfl_xor(sp, d, 64);
        }
        float inv = sp > 0.f ? 1.0f / sp : 0.f;
        float f[8];
#pragma unroll
        for (int i = 0; i < 8; ++i) {
            float t = a[i] * inv + b1s[sub * 8 + i];
            t = t > 0.f ? t : expm1f(t);
            t = t > 0.f ? t : expm1f(t);
            f[i] = t;
        }
        // epilogue GEMM via shfl broadcast: hf[s*8+i] lives in lane s (sub==s)
        float o = 0.f;
#pragma unroll
        for (int s = 0; s < 16; ++s) {
#pragma unroll
            for (int i = 0; i < 8; ++i) {
                float hf = __shfl(f[i], s, 64);
                o = fmaf(hf, W2s[(s * 8 + i) * NCLS + lane], o);
            }
        }
        h2[(size_t)v * NCLS + lane] = o;
        float pl = o * al2s[lane], pr = o * ar2s[lane];
#pragma unroll
        for (int d = 32; d > 0; d >>= 1) {
            pl += __shfl_xor(pl, d, 64);
            pr += __shfl_xor(pr, d, 64);
        }
        if (lane == 0) { el2[v] = pl; er2[v] = pr; }
    }
}

// ---------------- layer-2 aggregation: 4 edge-groups/wave, batch-4 -> d_out ----------------
__global__ __launch_bounds__(256) void aggregate2_kernel(const float* __restrict__ h2,
                                                         const float* __restrict__ el2,
                                                         const float* __restrict__ er2,
                                                         const int* __restrict__ row_off,
                                                         const int* __restrict__ sorted_src,
                                                         const float* __restrict__ b2,
                                                         float* __restrict__ out) {
    const int tid = threadIdx.x;
    const int v = blockIdx.x * 4 + (tid >> 6);
    if (v >= NNODES) return;
    const int lane = tid & 63, g = lane >> 4, sub = lane & 15;
    const int beg = row_off[v], end = row_off[v + 1];
    const float er_v = er2[v];
    float4 acc = {0, 0, 0, 0};
    float sp = 0.f;
    for (int j0 = beg; j0 < end; j0 += 64) {
        const int nj = min(64, end - j0);
        const int nit = (nj + 3) >> 2;
        bool valid = j0 + lane < end;
        int us = valid ? sorted_src[j0 + lane] : 0;
        float ev = valid ? el2[us] : 0.f;
        for (int ib = 0; ib < nit; ib += 4) {
            int j0i = g + 4 * (ib + 0), j1i = g + 4 * (ib + 1);
            int j2i = g + 4 * (ib + 2), j3i = g + 4 * (ib + 3);
            int u0 = __shfl(us, j0i & 63, 64);
            int u1 = __shfl(us, j1i & 63, 64);
            int u2 = __shfl(us, j2i & 63, 64);
            int u3 = __shfl(us, j3i & 63, 64);
            float e0 = __shfl(ev, j0i & 63, 64), e1 = __shfl(ev, j1i & 63, 64);
            float e2 = __shfl(ev, j2i & 63, 64), e3 = __shfl(ev, j3i & 63, 64);
            float4 h0 = *(const float4*)(h2 + (size_t)u0 * NCLS + sub * 4);
            float4 h1 = *(const float4*)(h2 + (size_t)u1 * NCLS + sub * 4);
            float4 hv2 = *(const float4*)(h2 + (size_t)u2 * NCLS + sub * 4);
            float4 h3 = *(const float4*)(h2 + (size_t)u3 * NCLS + sub * 4);
            float s0 = e0 + er_v; s0 = s0 > 0.f ? s0 : SLOPE * s0;
            float s1 = e1 + er_v; s1 = s1 > 0.f ? s1 : SLOPE * s1;
            float s2 = e2 + er_v; s2 = s2 > 0.f ? s2 : SLOPE * s2;
            float s3 = e3 + er_v; s3 = s3 > 0.f ? s3 : SLOPE * s3;
            float p0 = (j0i < nj) ? __expf(s0) : 0.f;
            float p1 = (j1i < nj) ? __expf(s1) : 0.f;
            float p2 = (j2i < nj) ? __expf(s2) : 0.f;
            float p3 = (j3i < nj) ? __expf(s3) : 0.f;
            sp += p0 + p1 + p2 + p3;
            acc.x = fmaf(p0, h0.x, acc.x); acc.y = fmaf(p0, h0.y, acc.y);
            acc.z = fmaf(p0, h0.z, acc.z); acc.w = fmaf(p0, h0.w, acc.w);
            acc.x = fmaf(p1, h1.x, acc.x); acc.y = fmaf(p1, h1.y, acc.y);
            acc.z = fmaf(p1, h1.z, acc.z); acc.w = fmaf(p1, h1.w, acc.w);
            acc.x = fmaf(p2, hv2.x, acc.x); acc.y = fmaf(p2, hv2.y, acc.y);
            acc.z = fmaf(p2, hv2.z, acc.z); acc.w = fmaf(p2, hv2.w, acc.w);
            acc.x = fmaf(p3, h3.x, acc.x); acc.y = fmaf(p3, h3.y, acc.y);
            acc.z = fmaf(p3, h3.z, acc.z); acc.w = fmaf(p3, h3.w, acc.w);
        }
    }
#pragma unroll
    for (int d = 16; d <= 32; d <<= 1) {
        acc.x += __shfl_xor(acc.x, d, 64); acc.y += __shfl_xor(acc.y, d, 64);
        acc.z += __shfl_xor(acc.z, d, 64); acc.w += __shfl_xor(acc.w, d, 64);
        sp += __shfl_xor(sp, d, 64);
    }
    if (g == 0) {
        float inv = sp > 0.f ? 1.0f / sp : 0.f;
        float4 bb = *(const float4*)(b2 + sub * 4);
        float4 o;
        o.x = acc.x * inv + bb.x; o.y = acc.y * inv + bb.y;
        o.z = acc.z * inv + bb.z; o.w = acc.w * inv + bb.w;
        *(float4*)(out + (size_t)v * NCLS + sub * 4) = o;
    }
}

extern "C" void kernel_launch(void* const* d_in, const int* in_sizes, int n_in,
                              void* d_out, int out_size, void* d_ws, size_t ws_size,
                              hipStream_t stream) {
    const float* x   = (const float*)d_in[0];
    const int*   src = (const int*)d_in[1];
    const int*   dst = (const int*)d_in[2];
    const float* W1  = (const float*)d_in[3];
    const float* al1 = (const float*)d_in[4];
    const float* ar1 = (const float*)d_in[5];
    const float* b1  = (const float*)d_in[6];
    const float* W2  = (const float*)d_in[7];
    const float* al2 = (const float*)d_in[8];
    const float* ar2 = (const float*)d_in[9];
    const float* b2  = (const float*)d_in[10];
    float* out = (float*)d_out;

    // workspace layout (all sub-arrays 16B-aligned), ~66 MB total
    float* h2  = (float*)d_ws;                               // N*NCLS fp32
    unsigned short* h1b = (unsigned short*)(h2 + (size_t)NNODES * NCLS);  // N*HID bf16
    float* el1 = (float*)(h1b + (size_t)NNODES * HID);       // N*HEADS
    float* er1 = el1 + (size_t)NNODES * HEADS;
    float* el2 = er1 + (size_t)NNODES * HEADS;               // N
    float* er2 = el2 + NNODES;
    int* counts     = (int*)(er2 + NNODES);                  // N
    int* row_off    = counts + NNODES;                       // N+1 (+pad)
    int* sorted_src = row_off + NNODES + 4;                  // E
    int* partials   = sorted_src + NEDGES;                   // 128
    short* W1T      = (short*)(partials + 128);              // HID*IN_DIM bf16

    const int nscan = (NNODES + 1023) / 1024;                // 98

    // ---- CSR build ----
    hipMemsetAsync(counts, 0, NNODES * sizeof(int), stream);
    hist_kernel<<<(NEDGES + 255) / 256, 256, 0, stream>>>(dst, counts);
    scan_partial_kernel<<<nscan, 256, 0, stream>>>(counts, partials);
    scan_root_kernel<<<1, 128, 0, stream>>>(partials, nscan);
    scan_final_kernel<<<nscan, 256, 0, stream>>>(counts, partials, row_off);
    hipMemsetAsync(counts, 0, NNODES * sizeof(int), stream);
    scatter_kernel<<<(NEDGES + 255) / 256, 256, 0, stream>>>(src, dst, row_off, counts, sorted_src);

    // ---- layer 1 ----
    prep_w1t_kernel<<<(IN_DIM * HID + 255) / 256, 256, 0, stream>>>(W1, W1T);
    gemm1_kernel<<<(NNODES + 127) / 128, 256, 0, stream>>>(x, W1T, h1b);
    attn_scores_kernel<<<(NNODES * HEADS + 255) / 256, 256, 0, stream>>>(h1b, al1, ar1, el1, er1);
    aggregate1_kernel<<<2048, 256, 0, stream>>>(h1b, el1, er1, row_off, sorted_src,
                                                W2, al2, ar2, b1, h2, el2, er2);

    // ---- layer 2 ----
    aggregate2_kernel<<<(NNODES + 3) / 4, 256, 0, stream>>>(h2, el2, er2, row_off, sorted_src,
                                                            b2, out);
}

// Round 8
// 398.059 us; speedup vs baseline: 11.2533x; 1.3937x over previous
//
#include <hip/hip_runtime.h>
#include <cstdint>
#include <cstddef>

#define NNODES 100000
#define NEDGES 1600000
#define IN_DIM 256
#define HID 128
#define HEADS 8
#define DH 16
#define NCLS 64
#define SLOPE 0.2f

typedef __attribute__((ext_vector_type(8))) short bf16x8;
typedef __attribute__((ext_vector_type(4))) float f32x4;

// float -> bf16 (round-to-nearest-even; inputs finite)
static __device__ __forceinline__ unsigned short f2bf(float f) {
    union { float f; uint32_t u; } c;
    c.f = f;
    uint32_t r = (c.u + 0x7FFFu + ((c.u >> 16) & 1u)) >> 16;
    return (unsigned short)r;
}
static __device__ __forceinline__ float bflo(unsigned int w) {
    union { uint32_t u; float f; } c; c.u = w << 16; return c.f;
}
static __device__ __forceinline__ float bfhi(unsigned int w) {
    union { uint32_t u; float f; } c; c.u = w & 0xFFFF0000u; return c.f;
}

// ---------------- W1 -> W1T bf16 [HID][IN_DIM] ----------------
__global__ __launch_bounds__(256) void prep_w1t_kernel(const float* __restrict__ W1,
                                                       short* __restrict__ W1T) {
    int idx = blockIdx.x * 256 + threadIdx.x;   // over IN_DIM*HID
    if (idx >= IN_DIM * HID) return;
    int k = idx >> 7;
    int n = idx & 127;
    W1T[n * IN_DIM + k] = (short)f2bf(W1[idx]);
}

// ---------------- W2 -> W2T bf16 [NCLS][HID] ----------------
__global__ __launch_bounds__(256) void prep_w2t_kernel(const float* __restrict__ W2,
                                                       short* __restrict__ W2T) {
    int idx = blockIdx.x * 256 + threadIdx.x;   // over HID*NCLS
    if (idx >= HID * NCLS) return;
    int k = idx >> 6;          // 0..127
    int n = idx & 63;          // 0..63
    W2T[n * HID + k] = (short)f2bf(W2[idx]);
}

// ---------------- bf16 MFMA GEMM1: h1b[M,128](bf16) = x[M,256] @ W1 ----------------
__global__ __launch_bounds__(256) void gemm1_kernel(const float* __restrict__ x,
                                                    const short* __restrict__ W1T,
                                                    unsigned short* __restrict__ h1b) {
    __shared__ short Asl[128 * 40];
    const int tid = threadIdx.x;
    const int brow = blockIdx.x * 128;
    const int wid = tid >> 6, lane = tid & 63;
    const int wm = (wid >> 1) * 64, wn = (wid & 1) * 64;
    const int mr = lane & 15;
    const int ks = lane >> 4;
    const int sr = tid >> 1;
    const int sch = tid & 1;
    const int grow = brow + sr;

    f32x4 acc[4][4];
#pragma unroll
    for (int i = 0; i < 4; ++i)
#pragma unroll
        for (int j = 0; j < 4; ++j) acc[i][j] = (f32x4){0.f, 0.f, 0.f, 0.f};

    for (int k0 = 0; k0 < IN_DIM; k0 += 32) {
        float4 v0 = {0,0,0,0}, v1 = {0,0,0,0}, v2 = {0,0,0,0}, v3 = {0,0,0,0};
        if (grow < NNODES) {
            const float* xp = x + (size_t)grow * IN_DIM + k0 + sch * 16;
            v0 = *(const float4*)(xp + 0);
            v1 = *(const float4*)(xp + 4);
            v2 = *(const float4*)(xp + 8);
            v3 = *(const float4*)(xp + 12);
        }
        bf16x8 p0, p1;
        p0[0] = (short)f2bf(v0.x); p0[1] = (short)f2bf(v0.y);
        p0[2] = (short)f2bf(v0.z); p0[3] = (short)f2bf(v0.w);
        p0[4] = (short)f2bf(v1.x); p0[5] = (short)f2bf(v1.y);
        p0[6] = (short)f2bf(v1.z); p0[7] = (short)f2bf(v1.w);
        p1[0] = (short)f2bf(v2.x); p1[1] = (short)f2bf(v2.y);
        p1[2] = (short)f2bf(v2.z); p1[3] = (short)f2bf(v2.w);
        p1[4] = (short)f2bf(v3.x); p1[5] = (short)f2bf(v3.y);
        p1[6] = (short)f2bf(v3.z); p1[7] = (short)f2bf(v3.w);
        __syncthreads();
        *(bf16x8*)(Asl + sr * 40 + sch * 16 + 0) = p0;
        *(bf16x8*)(Asl + sr * 40 + sch * 16 + 8) = p1;
        __syncthreads();

        bf16x8 af[4], bfr[4];
#pragma unroll
        for (int i = 0; i < 4; ++i)
            af[i] = *(const bf16x8*)(Asl + (wm + i * 16 + mr) * 40 + ks * 8);
#pragma unroll
        for (int j = 0; j < 4; ++j)
            bfr[j] = *(const bf16x8*)(W1T + (size_t)(wn + j * 16 + mr) * IN_DIM + k0 + ks * 8);
#pragma unroll
        for (int i = 0; i < 4; ++i)
#pragma unroll
            for (int j = 0; j < 4; ++j)
                acc[i][j] = __builtin_amdgcn_mfma_f32_16x16x32_bf16(af[i], bfr[j], acc[i][j], 0, 0, 0);
    }

#pragma unroll
    for (int i = 0; i < 4; ++i) {
#pragma unroll
        for (int j = 0; j < 4; ++j) {
            int col = wn + j * 16 + mr;
#pragma unroll
            for (int r = 0; r < 4; ++r) {
                int row = brow + wm + i * 16 + ks * 4 + r;
                if (row < NNODES) h1b[(size_t)row * HID + col] = f2bf(acc[i][j][r]);
            }
        }
    }
}

// ---------------- bf16 MFMA GEMM2: h2b = hf @ W2, fused el2/er2 ----------------
// block tile 128 rows x 64 cols, 4 waves (wave w: rows 32w..32w+31), K=128.
__global__ __launch_bounds__(256) void gemm2_kernel(const unsigned short* __restrict__ hfb,
                                                    const short* __restrict__ W2T,
                                                    const float* __restrict__ al2,
                                                    const float* __restrict__ ar2,
                                                    unsigned short* __restrict__ h2b,
                                                    float* __restrict__ el2,
                                                    float* __restrict__ er2) {
    __shared__ short A[128 * 136];   // 34.8 KB, stride 136 shorts (272B)
    const int tid = threadIdx.x;
    const int brow = blockIdx.x * 128;
    {
        int r = tid >> 1, half = tid & 1;
        int grow = brow + r;
        uint4* lp = (uint4*)(A + r * 136 + half * 64);
        if (grow < NNODES) {
            const uint4* gp = (const uint4*)(hfb + (size_t)grow * HID + half * 64);
#pragma unroll
            for (int i = 0; i < 8; ++i) lp[i] = gp[i];
        } else {
            uint4 z = {0, 0, 0, 0};
#pragma unroll
            for (int i = 0; i < 8; ++i) lp[i] = z;
        }
    }
    __syncthreads();

    const int wid = tid >> 6, lane = tid & 63;
    const int mr = lane & 15, ks = lane >> 4;
    const int wrow = wid * 32;

    f32x4 acc[2][4];
#pragma unroll
    for (int i = 0; i < 2; ++i)
#pragma unroll
        for (int j = 0; j < 4; ++j) acc[i][j] = (f32x4){0.f, 0.f, 0.f, 0.f};

#pragma unroll
    for (int kk = 0; kk < 4; ++kk) {
        const int k0 = kk * 32;
        bf16x8 af[2], bfr[4];
#pragma unroll
        for (int i = 0; i < 2; ++i)
            af[i] = *(const bf16x8*)(A + (wrow + i * 16 + mr) * 136 + k0 + ks * 8);
#pragma unroll
        for (int j = 0; j < 4; ++j)
            bfr[j] = *(const bf16x8*)(W2T + (size_t)(j * 16 + mr) * HID + k0 + ks * 8);
#pragma unroll
        for (int i = 0; i < 2; ++i)
#pragma unroll
            for (int j = 0; j < 4; ++j)
                acc[i][j] = __builtin_amdgcn_mfma_f32_16x16x32_bf16(af[i], bfr[j], acc[i][j], 0, 0, 0);
    }

    // attention-score vectors for this lane's columns
    float al2v[4], ar2v[4];
#pragma unroll
    for (int j = 0; j < 4; ++j) { al2v[j] = al2[j * 16 + mr]; ar2v[j] = ar2[j * 16 + mr]; }

    float pl[2][4] = {}, pr[2][4] = {};
    // store h2b (D layout: col = mr + 16j, row = wrow + 16i + ks*4 + r)
#pragma unroll
    for (int i = 0; i < 2; ++i) {
#pragma unroll
        for (int j = 0; j < 4; ++j) {
#pragma unroll
            for (int r = 0; r < 4; ++r) {
                float vvv = acc[i][j][r];
                pl[i][r] = fmaf(vvv, al2v[j], pl[i][r]);
                pr[i][r] = fmaf(vvv, ar2v[j], pr[i][r]);
                int row = brow + wrow + i * 16 + ks * 4 + r;
                if (row < NNODES) h2b[(size_t)row * NCLS + j * 16 + mr] = f2bf(vvv);
            }
        }
    }
    // reduce over the 16 col-lanes (mr = lane bits 0..3)
#pragma unroll
    for (int d = 1; d <= 8; d <<= 1) {
#pragma unroll
        for (int i = 0; i < 2; ++i)
#pragma unroll
            for (int r = 0; r < 4; ++r) {
                pl[i][r] += __shfl_xor(pl[i][r], d, 64);
                pr[i][r] += __shfl_xor(pr[i][r], d, 64);
            }
    }
    if (mr == 0) {
#pragma unroll
        for (int i = 0; i < 2; ++i)
#pragma unroll
            for (int r = 0; r < 4; ++r) {
                int row = brow + wrow + i * 16 + ks * 4 + r;
                if (row < NNODES) { el2[row] = pl[i][r]; er2[row] = pr[i][r]; }
            }
    }
}

// ---------------- CSR build ----------------
__global__ __launch_bounds__(256) void hist_kernel(const int* __restrict__ dst,
                                                   int* __restrict__ counts) {
    int e = blockIdx.x * 256 + threadIdx.x;
    if (e >= NEDGES) return;
    atomicAdd(&counts[dst[e]], 1);
}

__global__ __launch_bounds__(256) void scan_partial_kernel(const int* __restrict__ counts,
                                                           int* __restrict__ partials) {
    __shared__ int ws[4];
    const int t = threadIdx.x, lane = t & 63, wid = t >> 6;
    int base = blockIdx.x * 1024 + t * 4;
    int s = 0;
    if (base < NNODES) {
        int4 c = *(const int4*)(counts + base);
        s = c.x + c.y + c.z + c.w;
    }
#pragma unroll
    for (int d = 1; d < 64; d <<= 1) s += __shfl_xor(s, d, 64);
    if (lane == 0) ws[wid] = s;
    __syncthreads();
    if (t == 0) partials[blockIdx.x] = ws[0] + ws[1] + ws[2] + ws[3];
}

__global__ __launch_bounds__(128) void scan_root_kernel(int* __restrict__ partials, int nblk) {
    __shared__ int buf[128];
    const int t = threadIdx.x;
    buf[t] = (t < nblk) ? partials[t] : 0;
    __syncthreads();
#pragma unroll
    for (int d = 1; d < 128; d <<= 1) {
        int v = (t >= d) ? buf[t - d] : 0;
        __syncthreads();
        buf[t] += v;
        __syncthreads();
    }
    if (t < nblk) partials[t] = (t == 0) ? 0 : buf[t - 1];
}

__global__ __launch_bounds__(256) void scan_final_kernel(const int* __restrict__ counts,
                                                         const int* __restrict__ partials,
                                                         int* __restrict__ row_off) {
    __shared__ int ws[4];
    const int t = threadIdx.x, lane = t & 63, wid = t >> 6;
    int base = blockIdx.x * 1024 + t * 4;
    int4 c = {0, 0, 0, 0};
    if (base < NNODES) c = *(const int4*)(counts + base);
    int s0 = c.x, s01 = c.x + c.y, s012 = s01 + c.z, ts = s012 + c.w;
    int x = ts;
#pragma unroll
    for (int d = 1; d < 64; d <<= 1) {
        int y = __shfl_up(x, d, 64);
        if (lane >= d) x += y;
    }
    if (lane == 63) ws[wid] = x;
    __syncthreads();
    int woff = 0;
#pragma unroll
    for (int i = 0; i < 4; ++i) if (i < wid) woff += ws[i];
    int excl = partials[blockIdx.x] + woff + (x - ts);
    if (base < NNODES) {
        row_off[base + 0] = excl;
        row_off[base + 1] = excl + s0;
        row_off[base + 2] = excl + s01;
        row_off[base + 3] = excl + s012;
    }
    if (blockIdx.x == 0 && t == 0) row_off[NNODES] = NEDGES;
}

__global__ __launch_bounds__(256) void scatter_kernel(const int* __restrict__ src,
                                                      const int* __restrict__ dst,
                                                      const int* __restrict__ row_off,
                                                      int* __restrict__ cursor,
                                                      int* __restrict__ sorted_src) {
    int e = blockIdx.x * 256 + threadIdx.x;
    if (e >= NEDGES) return;
    int v = dst[e];
    int pos = row_off[v] + atomicAdd(&cursor[v], 1);
    sorted_src[pos] = src[e];
}

// ---------------- layer-1 attention scores (bf16 h1 in) ----------------
__global__ __launch_bounds__(256) void attn_scores_kernel(const unsigned short* __restrict__ h1b,
                                                          const float* __restrict__ al,
                                                          const float* __restrict__ ar,
                                                          float* __restrict__ el,
                                                          float* __restrict__ er) {
    int idx = blockIdx.x * 256 + threadIdx.x;   // node*HEADS + head
    if (idx >= NNODES * HEADS) return;
    int hd = idx & (HEADS - 1);
    const uint4* hp = (const uint4*)(h1b + (size_t)idx * DH);
    uint4 A = hp[0], B = hp[1];
    unsigned int w[8] = {A.x, A.y, A.z, A.w, B.x, B.y, B.z, B.w};
    float a = 0.f, c = 0.f;
#pragma unroll
    for (int i = 0; i < 8; ++i) {
        float lo = bflo(w[i]), hi = bfhi(w[i]);
        a = fmaf(lo, al[hd * DH + 2 * i], a);
        a = fmaf(hi, al[hd * DH + 2 * i + 1], a);
        c = fmaf(lo, ar[hd * DH + 2 * i], c);
        c = fmaf(hi, ar[hd * DH + 2 * i + 1], c);
    }
    el[idx] = a;
    er[idx] = c;
}

// ---------------- layer-1 aggregation: edge softmax-agg + bias + ELU^2 -> hf bf16 ----------------
__global__ __launch_bounds__(256) void aggregate1_kernel(const unsigned short* __restrict__ h1b,
                                                         const float* __restrict__ el1,
                                                         const float* __restrict__ er1,
                                                         const int* __restrict__ row_off,
                                                         const int* __restrict__ sorted_src,
                                                         const float* __restrict__ b1,
                                                         unsigned short* __restrict__ hfb) {
    __shared__ float b1s[HID];
    const int tid = threadIdx.x;
    if (tid < HID) b1s[tid] = b1[tid];
    __syncthreads();

    const int wid = tid >> 6, lane = tid & 63;
    const int g = lane >> 4, sub = lane & 15, hd = sub >> 1;

    for (int v = blockIdx.x * 4 + wid; v < NNODES; v += gridDim.x * 4) {
        const int beg = row_off[v], end = row_off[v + 1];
        const float er_v = er1[v * HEADS + hd];
        float a[8] = {0.f, 0.f, 0.f, 0.f, 0.f, 0.f, 0.f, 0.f};
        float sp = 0.f;
        for (int j0 = beg; j0 < end; j0 += 64) {
            const int nj = min(64, end - j0);
            const int nit = (nj + 3) >> 2;
            int us = (j0 + lane < end) ? sorted_src[j0 + lane] : 0;
            for (int ib = 0; ib < nit; ib += 4) {
                int j0i = g + 4 * (ib + 0), j1i = g + 4 * (ib + 1);
                int j2i = g + 4 * (ib + 2), j3i = g + 4 * (ib + 3);
                int u0 = __shfl(us, j0i & 63, 64);
                int u1 = __shfl(us, j1i & 63, 64);
                int u2 = __shfl(us, j2i & 63, 64);
                int u3 = __shfl(us, j3i & 63, 64);
                uint4 w0 = *(const uint4*)(h1b + (size_t)u0 * HID + sub * 8);
                uint4 w1 = *(const uint4*)(h1b + (size_t)u1 * HID + sub * 8);
                uint4 w2 = *(const uint4*)(h1b + (size_t)u2 * HID + sub * 8);
                uint4 w3 = *(const uint4*)(h1b + (size_t)u3 * HID + sub * 8);
                float e0 = el1[u0 * HEADS + hd], e1 = el1[u1 * HEADS + hd];
                float e2 = el1[u2 * HEADS + hd], e3 = el1[u3 * HEADS + hd];
                float s0 = e0 + er_v; s0 = s0 > 0.f ? s0 : SLOPE * s0;
                float s1 = e1 + er_v; s1 = s1 > 0.f ? s1 : SLOPE * s1;
                float s2 = e2 + er_v; s2 = s2 > 0.f ? s2 : SLOPE * s2;
                float s3 = e3 + er_v; s3 = s3 > 0.f ? s3 : SLOPE * s3;
                float p0 = (j0i < nj) ? __expf(s0) : 0.f;
                float p1 = (j1i < nj) ? __expf(s1) : 0.f;
                float p2 = (j2i < nj) ? __expf(s2) : 0.f;
                float p3 = (j3i < nj) ? __expf(s3) : 0.f;
                sp += p0 + p1 + p2 + p3;
#define ACC8(P, W) \
                a[0] = fmaf(P, bflo(W.x), a[0]); a[1] = fmaf(P, bfhi(W.x), a[1]); \
                a[2] = fmaf(P, bflo(W.y), a[2]); a[3] = fmaf(P, bfhi(W.y), a[3]); \
                a[4] = fmaf(P, bflo(W.z), a[4]); a[5] = fmaf(P, bfhi(W.z), a[5]); \
                a[6] = fmaf(P, bflo(W.w), a[6]); a[7] = fmaf(P, bfhi(W.w), a[7]);
                ACC8(p0, w0) ACC8(p1, w1) ACC8(p2, w2) ACC8(p3, w3)
#undef ACC8
            }
        }
#pragma unroll
        for (int d = 16; d <= 32; d <<= 1) {
#pragma unroll
            for (int i = 0; i < 8; ++i) a[i] += __shfl_xor(a[i], d, 64);
            sp += __shfl_xor(sp, d, 64);
        }
        float inv = sp > 0.f ? 1.0f / sp : 0.f;
        float f[8];
#pragma unroll
        for (int i = 0; i < 8; ++i) {
            float t = a[i] * inv + b1s[sub * 8 + i];
            t = t > 0.f ? t : expm1f(t);
            t = t > 0.f ? t : expm1f(t);
            f[i] = t;
        }
        if (g == 0) {
            uint4 w;
            w.x = (unsigned)f2bf(f[0]) | ((unsigned)f2bf(f[1]) << 16);
            w.y = (unsigned)f2bf(f[2]) | ((unsigned)f2bf(f[3]) << 16);
            w.z = (unsigned)f2bf(f[4]) | ((unsigned)f2bf(f[5]) << 16);
            w.w = (unsigned)f2bf(f[6]) | ((unsigned)f2bf(f[7]) << 16);
            *(uint4*)(hfb + (size_t)v * HID + sub * 8) = w;
        }
    }
}

// ---------------- layer-2 aggregation: 8 edge-groups x 8 lanes, bf16 h2 -> d_out ----------------
__global__ __launch_bounds__(256) void aggregate2_kernel(const unsigned short* __restrict__ h2b,
                                                         const float* __restrict__ el2,
                                                         const float* __restrict__ er2,
                                                         const int* __restrict__ row_off,
                                                         const int* __restrict__ sorted_src,
                                                         const float* __restrict__ b2,
                                                         float* __restrict__ out) {
    const int tid = threadIdx.x;
    const int v = blockIdx.x * 4 + (tid >> 6);
    if (v >= NNODES) return;
    const int lane = tid & 63, g = lane >> 3, sub = lane & 7;
    const int beg = row_off[v], end = row_off[v + 1];
    const float er_v = er2[v];
    float a[8] = {0.f, 0.f, 0.f, 0.f, 0.f, 0.f, 0.f, 0.f};
    float sp = 0.f;
    for (int j0 = beg; j0 < end; j0 += 64) {
        const int nj = min(64, end - j0);
        const int nit = (nj + 7) >> 3;
        bool valid = j0 + lane < end;
        int us = valid ? sorted_src[j0 + lane] : 0;
        float ev = valid ? el2[us] : 0.f;
        for (int ib = 0; ib < nit; ib += 4) {
            int j0i = g + 8 * (ib + 0), j1i = g + 8 * (ib + 1);
            int j2i = g + 8 * (ib + 2), j3i = g + 8 * (ib + 3);
            int u0 = __shfl(us, j0i & 63, 64);
            int u1 = __shfl(us, j1i & 63, 64);
            int u2 = __shfl(us, j2i & 63, 64);
            int u3 = __shfl(us, j3i & 63, 64);
            float e0 = __shfl(ev, j0i & 63, 64), e1 = __shfl(ev, j1i & 63, 64);
            float e2 = __shfl(ev, j2i & 63, 64), e3 = __shfl(ev, j3i & 63, 64);
            uint4 w0 = *(const uint4*)(h2b + (size_t)u0 * NCLS + sub * 8);
            uint4 w1 = *(const uint4*)(h2b + (size_t)u1 * NCLS + sub * 8);
            uint4 w2 = *(const uint4*)(h2b + (size_t)u2 * NCLS + sub * 8);
            uint4 w3 = *(const uint4*)(h2b + (size_t)u3 * NCLS + sub * 8);
            float s0 = e0 + er_v; s0 = s0 > 0.f ? s0 : SLOPE * s0;
            float s1 = e1 + er_v; s1 = s1 > 0.f ? s1 : SLOPE * s1;
            float s2 = e2 + er_v; s2 = s2 > 0.f ? s2 : SLOPE * s2;
            float s3 = e3 + er_v; s3 = s3 > 0.f ? s3 : SLOPE * s3;
            float p0 = (j0i < nj) ? __expf(s0) : 0.f;
            float p1 = (j1i < nj) ? __expf(s1) : 0.f;
            float p2 = (j2i < nj) ? __expf(s2) : 0.f;
            float p3 = (j3i < nj) ? __expf(s3) : 0.f;
            sp += p0 + p1 + p2 + p3;
#define ACC8(P, W) \
            a[0] = fmaf(P, bflo(W.x), a[0]); a[1] = fmaf(P, bfhi(W.x), a[1]); \
            a[2] = fmaf(P, bflo(W.y), a[2]); a[3] = fmaf(P, bfhi(W.y), a[3]); \
            a[4] = fmaf(P, bflo(W.z), a[4]); a[5] = fmaf(P, bfhi(W.z), a[5]); \
            a[6] = fmaf(P, bflo(W.w), a[6]); a[7] = fmaf(P, bfhi(W.w), a[7]);
            ACC8(p0, w0) ACC8(p1, w1) ACC8(p2, w2) ACC8(p3, w3)
#undef ACC8
        }
    }
#pragma unroll
    for (int d = 8; d <= 32; d <<= 1) {
#pragma unroll
        for (int i = 0; i < 8; ++i) a[i] += __shfl_xor(a[i], d, 64);
        sp += __shfl_xor(sp, d, 64);
    }
    if (g == 0) {
        float inv = sp > 0.f ? 1.0f / sp : 0.f;
        float4 b0 = *(const float4*)(b2 + sub * 8);
        float4 b1v = *(const float4*)(b2 + sub * 8 + 4);
        float4 o0, o1;
        o0.x = a[0] * inv + b0.x; o0.y = a[1] * inv + b0.y;
        o0.z = a[2] * inv + b0.z; o0.w = a[3] * inv + b0.w;
        o1.x = a[4] * inv + b1v.x; o1.y = a[5] * inv + b1v.y;
        o1.z = a[6] * inv + b1v.z; o1.w = a[7] * inv + b1v.w;
        *(float4*)(out + (size_t)v * NCLS + sub * 8) = o0;
        *(float4*)(out + (size_t)v * NCLS + sub * 8 + 4) = o1;
    }
}

extern "C" void kernel_launch(void* const* d_in, const int* in_sizes, int n_in,
                              void* d_out, int out_size, void* d_ws, size_t ws_size,
                              hipStream_t stream) {
    const float* x   = (const float*)d_in[0];
    const int*   src = (const int*)d_in[1];
    const int*   dst = (const int*)d_in[2];
    const float* W1  = (const float*)d_in[3];
    const float* al1 = (const float*)d_in[4];
    const float* ar1 = (const float*)d_in[5];
    const float* b1  = (const float*)d_in[6];
    const float* W2  = (const float*)d_in[7];
    const float* al2 = (const float*)d_in[8];
    const float* ar2 = (const float*)d_in[9];
    const float* b2  = (const float*)d_in[10];
    float* out = (float*)d_out;

    // workspace layout (16B-aligned sub-arrays), ~79 MB total
    float* el1 = (float*)d_ws;                               // N*HEADS
    float* er1 = el1 + (size_t)NNODES * HEADS;               // N*HEADS
    float* el2 = er1 + (size_t)NNODES * HEADS;               // N
    float* er2 = el2 + NNODES;                               // N
    unsigned short* h1b = (unsigned short*)(er2 + NNODES);   // N*HID bf16
    unsigned short* hfb = h1b + (size_t)NNODES * HID;        // N*HID bf16
    unsigned short* h2b = hfb + (size_t)NNODES * HID;        // N*NCLS bf16
    int* counts     = (int*)(h2b + (size_t)NNODES * NCLS);   // N
    int* row_off    = counts + NNODES;                       // N+1 (+pad)
    int* sorted_src = row_off + NNODES + 4;                  // E
    int* partials   = sorted_src + NEDGES;                   // 128
    short* W1T      = (short*)(partials + 128);              // HID*IN_DIM bf16
    short* W2T      = W1T + (size_t)HID * IN_DIM;            // NCLS*HID bf16

    const int nscan = (NNODES + 1023) / 1024;                // 98

    // ---- CSR build ----
    hipMemsetAsync(counts, 0, NNODES * sizeof(int), stream);
    hist_kernel<<<(NEDGES + 255) / 256, 256, 0, stream>>>(dst, counts);
    scan_partial_kernel<<<nscan, 256, 0, stream>>>(counts, partials);
    scan_root_kernel<<<1, 128, 0, stream>>>(partials, nscan);
    scan_final_kernel<<<nscan, 256, 0, stream>>>(counts, partials, row_off);
    hipMemsetAsync(counts, 0, NNODES * sizeof(int), stream);
    scatter_kernel<<<(NEDGES + 255) / 256, 256, 0, stream>>>(src, dst, row_off, counts, sorted_src);

    // ---- layer 1 ----
    prep_w1t_kernel<<<(IN_DIM * HID + 255) / 256, 256, 0, stream>>>(W1, W1T);
    prep_w2t_kernel<<<(HID * NCLS + 255) / 256, 256, 0, stream>>>(W2, W2T);
    gemm1_kernel<<<(NNODES + 127) / 128, 256, 0, stream>>>(x, W1T, h1b);
    attn_scores_kernel<<<(NNODES * HEADS + 255) / 256, 256, 0, stream>>>(h1b, al1, ar1, el1, er1);
    aggregate1_kernel<<<2048, 256, 0, stream>>>(h1b, el1, er1, row_off, sorted_src, b1, hfb);

    // ---- layer 2 ----
    gemm2_kernel<<<(NNODES + 127) / 128, 256, 0, stream>>>(hfb, W2T, al2, ar2, h2b, el2, er2);
    aggregate2_kernel<<<(NNODES + 3) / 4, 256, 0, stream>>>(h2b, el2, er2, row_off, sorted_src,
                                                            b2, out);
}